// Round 7
// baseline (509.061 us; speedup 1.0000x reference)
//
#include <hip/hip_runtime.h>
#include <hip/hip_bf16.h>

// Problem constants (B,D,H,W,C) = (2,32,56,56,96); WS=(2,7,7), SS=(1,3,3)
#define NTOK   200704      // B*D*H*W
#define NWIN   2048        // B * 1024 windows
#define NT     98          // tokens per window (2*7*7)
#define CCH    96
#define HID    384

typedef __attribute__((ext_vector_type(8))) short bf16x8;   // 8 bf16, 4 VGPRs
typedef __attribute__((ext_vector_type(4))) short s16x4;    // 4 bf16, 8 bytes
typedef __attribute__((ext_vector_type(4))) float f32x4;
typedef __attribute__((ext_vector_type(2))) float f32x2;
typedef __attribute__((ext_vector_type(4))) int   i32x4;

#define MFMA(a, b, c) __builtin_amdgcn_mfma_f32_16x16x32_bf16((a), (b), (c), 0, 0, 0)

__device__ __forceinline__ float bf2f(__hip_bfloat16 v) { return __bfloat162float(v); }

__device__ __forceinline__ short f2bf_s(float v) {
  __hip_bfloat16 h = __float2bfloat16(v);
  return *reinterpret_cast<short*>(&h);
}

__device__ __forceinline__ unsigned pack2(float a, float b) {
  unsigned ua = (unsigned short)f2bf_s(a);
  unsigned ub = (unsigned short)f2bf_s(b);
  return ua | (ub << 16);
}

// gelu(x) ~= x * sigmoid(1.5957691x + 0.0713548x^3)  (tanh-form GELU)
__device__ __forceinline__ float gelu_f(float v) {
  float u = v * (1.5957691216057308f + 0.0713548162726f * v * v);
  return __fdividef(v, 1.f + __expf(-u));
}

// ---------------- Kernel 0: convert weights to bf16 -----------------------
__global__ __launch_bounds__(256) void k0_cvt(
    const float* __restrict__ w1, const float* __restrict__ w2,
    const float* __restrict__ qkvw, const float* __restrict__ pw,
    __hip_bfloat16* __restrict__ w1b, __hip_bfloat16* __restrict__ w2b,
    __hip_bfloat16* __restrict__ qkvwb, __hip_bfloat16* __restrict__ pwb) {
  int i = blockIdx.x * 256 + threadIdx.x;
  if (i < HID * CCH) {
    w1b[i] = __float2bfloat16(w1[i]);
    w2b[i] = __float2bfloat16(w2[i]);
  }
  if (i < 3 * CCH * CCH) qkvwb[i] = __float2bfloat16(qkvw[i]);
  if (i < CCH * CCH)     pwb[i]   = __float2bfloat16(pw[i]);
}

// ---------------- Kernel 1: LN1 + shift + window partition -> xw (bf16) ----
__global__ __launch_bounds__(256) void k1_ln_window(
    const float* __restrict__ x, const float* __restrict__ g,
    const float* __restrict__ bt, __hip_bfloat16* __restrict__ xw) {
  int token = blockIdx.x * 8 + (threadIdx.x >> 5);
  int lane = threadIdx.x & 31;
  if (token >= NTOK) return;
  int wb = token / NT;
  int n  = token - wb * NT;
  int b = wb >> 10;
  int rem = wb & 1023;
  int wd = rem >> 6, wh = (rem >> 3) & 7, ww = rem & 7;
  int id = n / 49, ih = (n / 7) % 7, iw = n % 7;
  int dd = wd * 2 + id + 1; if (dd >= 32) dd -= 32;
  int hh = wh * 7 + ih + 3; if (hh >= 56) hh -= 56;
  int w2 = ww * 7 + iw + 3; if (w2 >= 56) w2 -= 56;
  const float* src = x + ((((size_t)b * 32 + dd) * 56 + hh) * 56 + w2) * CCH;
  float v0 = src[lane], v1 = src[lane + 32], v2 = src[lane + 64];
  float s = v0 + v1 + v2, ss = v0 * v0 + v1 * v1 + v2 * v2;
  #pragma unroll
  for (int off = 16; off; off >>= 1) {
    s  += __shfl_xor(s,  off, 32);
    ss += __shfl_xor(ss, off, 32);
  }
  float m   = s * (1.f / 96.f);
  float inv = rsqrtf(ss * (1.f / 96.f) - m * m + 1e-5f);
  __hip_bfloat16* dst = xw + (size_t)token * CCH;
  dst[lane]      = __float2bfloat16((v0 - m) * inv * g[lane]      + bt[lane]);
  dst[lane + 32] = __float2bfloat16((v1 - m) * inv * g[lane + 32] + bt[lane + 32]);
  dst[lane + 64] = __float2bfloat16((v2 - m) * inv * g[lane + 64] + bt[lane + 64]);
}

// ---------------- Kernel 2: per-(window,head) MFMA attention --------------
// No Xs staging, operand-swapped QKV/QK^T/PV, register P, arithmetic mask.
// LDS 25.7KB, 1 barrier. (validated Round 5)
#define QK_S 40     // Q/K row stride (elems)
#define VT_S 120    // V^T row stride (elems); cols 0..111 used
__global__ __launch_bounds__(256, 4) void k2_attn(
    const __hip_bfloat16* __restrict__ xw, const __hip_bfloat16* __restrict__ qkvwb,
    const float* __restrict__ qkv_b, __hip_bfloat16* __restrict__ obuf) {
  __shared__ __align__(16) __hip_bfloat16 Qs[112 * QK_S];   // [token][dim]
  __shared__ __align__(16) __hip_bfloat16 Ks[112 * QK_S];   // [token][dim]
  __shared__ __align__(16) __hip_bfloat16 Vts[32 * VT_S];   // [dim][token]
  __shared__ unsigned char ridL[112];
  int bid = blockIdx.x, tid = threadIdx.x;
  int wb = bid / 3, h = bid - wb * 3;
  int wid = tid >> 6, lane = tid & 63, lr = lane & 15, lq = lane >> 4;
  int mw = wb & 1023;
  int wd = mw >> 6, wh = (mw >> 3) & 7, ww = mw & 7;
  bool hasmask = (wd == 15) || (wh == 7) || (ww == 7);
  const __hip_bfloat16* xp = xw + (size_t)wb * (NT * CCH);
  int h32 = h * 32;

  if (tid < 112) {
    int n = tid < NT ? tid : NT - 1;
    int id = n / 49, r2 = n - id * 49, ih = r2 / 7, iw = r2 - ih * 7;
    int ud = wd * 2 + id, uh = wh * 7 + ih, uw = ww * 7 + iw;
    int dr = (ud < 30) ? 0 : (ud == 30 ? 1 : 2);
    int hr = (uh < 49) ? 0 : (uh < 53 ? 1 : 2);
    int wr = (uw < 49) ? 0 : (uw < 53 ? 1 : 2);
    ridL[tid] = (unsigned char)(dr * 9 + hr * 3 + wr);
  }

  // ---- QKV: 7 token-tiles x 6 out-tiles (Q0,Q1,K0,K1,V0,V1), K=96 ----
  for (int job = wid; job < 42; job += 4) {
    int mt = job / 6, ct = job - (job / 6) * 6;
    int tok = mt * 16 + lr;
    int tokc = tok < NT ? tok : NT - 1;       // clamp: rows >=98 duplicate 97
    const __hip_bfloat16* xrow = xp + (size_t)tokc * CCH;
    bf16x8 xf0 = *(const bf16x8*)(xrow + lq * 8);
    bf16x8 xf1 = *(const bf16x8*)(xrow + 32 + lq * 8);
    bf16x8 xf2 = *(const bf16x8*)(xrow + 64 + lq * 8);
    if (ct < 4) {
      int which = ct >> 1;                    // 0=Q, 1=K
      int grow0 = which * CCH + h32 + (ct & 1) * 16;
      const __hip_bfloat16* wr0 = qkvwb + (size_t)(grow0 + lr) * CCH;
      f32x4 acc = *(const f32x4*)&qkv_b[grow0 + lq * 4];
      acc = MFMA(*(const bf16x8*)(wr0 + lq * 8),      xf0, acc);
      acc = MFMA(*(const bf16x8*)(wr0 + 32 + lq * 8), xf1, acc);
      acc = MFMA(*(const bf16x8*)(wr0 + 64 + lq * 8), xf2, acc);
      if (which == 0) {
        #pragma unroll
        for (int r = 0; r < 4; ++r) acc[r] *= 0.17677669529663689f;
      }
      s16x4 pk4;
      #pragma unroll
      for (int r = 0; r < 4; ++r) pk4[r] = f2bf_s(acc[r]);
      __hip_bfloat16* dst = (which == 0) ? Qs : Ks;
      *(s16x4*)&dst[tok * QK_S + (ct & 1) * 16 + lq * 4] = pk4;
    } else {
      int dt = ct & 1;
      int vrow = 2 * CCH + h32 + dt * 16 + lr;
      const __hip_bfloat16* wv = qkvwb + (size_t)vrow * CCH;
      float bv = qkv_b[vrow];
      f32x4 acc = {bv, bv, bv, bv};
      acc = MFMA(xf0, *(const bf16x8*)(wv + lq * 8),      acc);
      acc = MFMA(xf1, *(const bf16x8*)(wv + 32 + lq * 8), acc);
      acc = MFMA(xf2, *(const bf16x8*)(wv + 64 + lq * 8), acc);
      s16x4 pk4;
      #pragma unroll
      for (int r = 0; r < 4; ++r) pk4[r] = f2bf_s(acc[r]);
      *(s16x4*)&Vts[(dt * 16 + lr) * VT_S + mt * 16 + lq * 4] = pk4;
    }
  }
  __syncthreads();

  // ---- attention: S^T = K*Q^T; softmax per lane (query=lr); O^T = V^T*P^T
  for (int mt = wid; mt < 7; mt += 4) {
    bf16x8 qf = *(const bf16x8*)&Qs[(mt * 16 + lr) * QK_S + lq * 8];
    f32x4 s[7];
    #pragma unroll
    for (int nt = 0; nt < 7; ++nt) s[nt] = {0.f, 0.f, 0.f, 0.f};
    #pragma unroll
    for (int nt = 0; nt < 7; ++nt) {
      bf16x8 kf = *(const bf16x8*)&Ks[(nt * 16 + lr) * QK_S + lq * 8];
      s[nt] = MFMA(kf, qf, s[nt]);   // lane: key = nt*16+lq*4+r, query = mt*16+lr
    }
    if (hasmask) {
      int rq = ridL[mt * 16 + lr];
      #pragma unroll
      for (int nt = 0; nt < 7; ++nt)
        #pragma unroll
        for (int r = 0; r < 4; ++r)
          s[nt][r] += (ridL[nt * 16 + lq * 4 + r] != rq) ? -100.f : 0.f;
    }
    #pragma unroll
    for (int r = 0; r < 4; ++r)   // kill keys 98..111
      s[6][r] = (lq * 4 + r >= 2) ? -1e30f : s[6][r];
    float m = s[0][0];
    #pragma unroll
    for (int nt = 0; nt < 7; ++nt)
      #pragma unroll
      for (int r = 0; r < 4; ++r) m = fmaxf(m, s[nt][r]);
    m = fmaxf(m, __shfl_xor(m, 16));
    m = fmaxf(m, __shfl_xor(m, 32));
    float sum = 0.f;
    #pragma unroll
    for (int nt = 0; nt < 7; ++nt)
      #pragma unroll
      for (int r = 0; r < 4; ++r) {
        float e = __expf(s[nt][r] - m);
        s[nt][r] = e;
        sum += e;
      }
    sum += __shfl_xor(sum, 16);
    sum += __shfl_xor(sum, 32);
    float inv = 1.f / sum;
    #pragma unroll
    for (int nt = 0; nt < 7; ++nt)
      #pragma unroll
      for (int r = 0; r < 4; ++r) s[nt][r] *= inv;
    unsigned pk[6][2];
    #pragma unroll
    for (int nt = 0; nt < 6; ++nt) {
      pk[nt][0] = pack2(s[nt][0], s[nt][1]);
      pk[nt][1] = pack2(s[nt][2], s[nt][3]);
    }
    // PV: build P^T b-frags via shfl (elem j lane l = P[q=lr][ks*32+lq*8+j])
    f32x4 o0 = {0.f, 0.f, 0.f, 0.f}, o1 = {0.f, 0.f, 0.f, 0.f};
    int srcA = lr + ((lq & 1) << 5);
    bool hi = (lq & 2) != 0;
    #pragma unroll
    for (int ks = 0; ks < 3; ++ks) {
      int a0 = __shfl((int)pk[2 * ks][0], srcA);
      int b0 = __shfl((int)pk[2 * ks + 1][0], srcA);
      int a1 = __shfl((int)pk[2 * ks][1], srcA);
      int b1 = __shfl((int)pk[2 * ks + 1][1], srcA);
      int a2 = __shfl((int)pk[2 * ks][0], srcA + 16);
      int b2 = __shfl((int)pk[2 * ks + 1][0], srcA + 16);
      int a3 = __shfl((int)pk[2 * ks][1], srcA + 16);
      int b3 = __shfl((int)pk[2 * ks + 1][1], srcA + 16);
      i32x4 wv4;
      wv4[0] = hi ? b0 : a0;
      wv4[1] = hi ? b1 : a1;
      wv4[2] = hi ? b2 : a2;
      wv4[3] = hi ? b3 : a3;
      bf16x8 pf = __builtin_bit_cast(bf16x8, wv4);
      o0 = MFMA(*(const bf16x8*)&Vts[lr * VT_S + ks * 32 + lq * 8], pf, o0);
      o1 = MFMA(*(const bf16x8*)&Vts[(16 + lr) * VT_S + ks * 32 + lq * 8], pf, o1);
    }
    float p96 = __shfl(s[6][0], lr);
    float p97 = __shfl(s[6][1], lr);
    #pragma unroll
    for (int r = 0; r < 4; ++r) {
      int d0 = lq * 4 + r, d1 = 16 + lq * 4 + r;
      o0[r] += p96 * bf2f(Vts[d0 * VT_S + 96]) + p97 * bf2f(Vts[d0 * VT_S + 97]);
      o1[r] += p96 * bf2f(Vts[d1 * VT_S + 96]) + p97 * bf2f(Vts[d1 * VT_S + 97]);
    }
    int q = mt * 16 + lr;
    if (q < NT) {
      __hip_bfloat16* ob = obuf + ((size_t)wb * NT + q) * CCH + h32;
      s16x4 w0, w1;
      #pragma unroll
      for (int r = 0; r < 4; ++r) { w0[r] = f2bf_s(o0[r]); w1[r] = f2bf_s(o1[r]); }
      *(s16x4*)(ob + lq * 4) = w0;
      *(s16x4*)(ob + 16 + lq * 4) = w1;
    }
  }
}

// ---------------- Kernel 3: MFMA proj + window-reverse + residual ---------
// Operand-swapped proj (D = Wp * os^T): lane holds ONE token and 4
// consecutive channels -> one address calc + f32x4 residual RMW. (R6 win)
#define XS_S 104
__global__ __launch_bounds__(256) void k3_proj(
    const __hip_bfloat16* __restrict__ obuf, const float* __restrict__ x,
    const __hip_bfloat16* __restrict__ pwb, const float* __restrict__ pb,
    float* __restrict__ out) {
  __shared__ __align__(16) __hip_bfloat16 os[112 * XS_S];
  int wb = blockIdx.x, tid = threadIdx.x;
  int wid = tid >> 6, lane = tid & 63, lr = lane & 15, lq = lane >> 4;
  const __hip_bfloat16* src = obuf + (size_t)wb * (NT * CCH);
  for (int q = tid; q < 112 * 12; q += 256) {
    int n = q / 12, g = q - n * 12;
    bf16x8 v = {0, 0, 0, 0, 0, 0, 0, 0};
    if (n < NT) v = *(const bf16x8*)(src + n * CCH + g * 8);
    *(bf16x8*)&os[n * XS_S + g * 8] = v;
  }
  __syncthreads();
  int b = wb >> 10, rem = wb & 1023;
  int wd = rem >> 6, wh = (rem >> 3) & 7, ww = rem & 7;
  for (int job = wid; job < 42; job += 4) {
    int mt = job / 6, ct = job - (job / 6) * 6;
    f32x4 acc = *(const f32x4*)&pb[ct * 16 + lq * 4];
    const __hip_bfloat16* wrow = pwb + (size_t)(ct * 16 + lr) * CCH;
    #pragma unroll
    for (int ks = 0; ks < 3; ++ks) {
      bf16x8 osf = *(const bf16x8*)&os[(mt * 16 + lr) * XS_S + ks * 32 + lq * 8];
      bf16x8 wf  = *(const bf16x8*)(wrow + ks * 32 + lq * 8);
      acc = MFMA(wf, osf, acc);   // D: col=token(lr), row=ch(lq*4+r)
    }
    int token = mt * 16 + lr;
    if (token < NT) {
      int id = token / 49, r2 = token - id * 49;
      int ih = r2 / 7, iw = r2 - ih * 7;
      int dd = wd * 2 + id + 1; if (dd >= 32) dd -= 32;
      int hh = wh * 7 + ih + 3; if (hh >= 56) hh -= 56;
      int w2 = ww * 7 + iw + 3; if (w2 >= 56) w2 -= 56;
      size_t gi = ((((size_t)b * 32 + dd) * 56 + hh) * 56 + w2) * CCH + ct * 16 + lq * 4;
      f32x4 xv = *(const f32x4*)&x[gi];
      *(f32x4*)&out[gi] = xv + acc;
    }
  }
}

// ---------------- Kernel 4: MFMA MLP, H kept in REGISTERS -----------------
// 64 tokens/block, 4 waves; each wave owns 16 tokens END-TO-END:
// fc1' (swapped: lane = token lr, hid lq*4+r) -> GELU -> pack bf16 pairs ->
// dual-shfl+select (k2-validated pattern) builds fc2 B-frags (8 consecutive
// hid of token lr) -> fc2 swapped (lane = token lr, 4 consecutive chs) ->
// f32x4 residual RMW. NO Ht LDS, NO mid barrier, ~0 bank conflicts.
// Two hid-halves (192 each) bound live registers. LDS = Xb 13.3KB only.
#define XB_S 104
__global__ __launch_bounds__(256) void k4_mlp(
    float* __restrict__ io, const float* __restrict__ g, const float* __restrict__ bt,
    const __hip_bfloat16* __restrict__ w1b, const float* __restrict__ b1,
    const __hip_bfloat16* __restrict__ w2b, const float* __restrict__ b2) {
  __shared__ __align__(16) __hip_bfloat16 Xb[64 * XB_S];   // 13312 B
  int tid = threadIdx.x;
  size_t base = (size_t)blockIdx.x * 64 * CCH;
  // LN (round-5 proven form): 8 groups x 32 lanes, 8 tokens each
  {
    int grp = tid >> 5, lane = tid & 31;
    #pragma unroll
    for (int t0 = 0; t0 < 8; ++t0) {
      int t = grp + t0 * 8;
      const float* src = io + base + (size_t)t * CCH;
      float v0 = src[lane], v1 = src[lane + 32], v2 = src[lane + 64];
      float s = v0 + v1 + v2, ss = v0 * v0 + v1 * v1 + v2 * v2;
      #pragma unroll
      for (int off = 16; off; off >>= 1) {
        s  += __shfl_xor(s,  off, 32);
        ss += __shfl_xor(ss, off, 32);
      }
      float m   = s * (1.f / 96.f);
      float inv = rsqrtf(ss * (1.f / 96.f) - m * m + 1e-5f);
      Xb[t * XB_S + lane]      = __float2bfloat16((v0 - m) * inv * g[lane]      + bt[lane]);
      Xb[t * XB_S + lane + 32] = __float2bfloat16((v1 - m) * inv * g[lane + 32] + bt[lane + 32]);
      Xb[t * XB_S + lane + 64] = __float2bfloat16((v2 - m) * inv * g[lane + 64] + bt[lane + 64]);
    }
  }
  __syncthreads();
  int wid = tid >> 6, lane = tid & 63, lr = lane & 15, lq = lane >> 4;
  // X b-frags for this wave's 16 tokens (token = wid*16 + lr)
  bf16x8 xb[3];
  #pragma unroll
  for (int ks = 0; ks < 3; ++ks)
    xb[ks] = *(const bf16x8*)&Xb[(wid * 16 + lr) * XB_S + ks * 32 + lq * 8];
  // fc2 accumulators: lane = token lr, chs ct*16 + lq*4 .. +3
  f32x4 acc2[6];
  #pragma unroll
  for (int ct = 0; ct < 6; ++ct)
    acc2[ct] = *(const f32x4*)&b2[ct * 16 + lq * 4];
  int srcA = ((lq & 1) << 5) + lr;
  bool hiSel = (lq & 2) != 0;
  #pragma unroll
  for (int h = 0; h < 2; ++h) {
    // fc1' for hid half h (192 hid): 12 tiles x 3 ks
    f32x4 acc[12];
    #pragma unroll
    for (int nt = 0; nt < 12; ++nt)
      acc[nt] = *(const f32x4*)&b1[(h * 12 + nt) * 16 + lq * 4];
    #pragma unroll
    for (int nt = 0; nt < 12; ++nt) {
      const __hip_bfloat16* wrow = w1b + (size_t)((h * 12 + nt) * 16 + lr) * CCH;
      #pragma unroll
      for (int ks = 0; ks < 3; ++ks) {
        bf16x8 wf = *(const bf16x8*)(wrow + ks * 32 + lq * 8);
        acc[nt] = MFMA(wf, xb[ks], acc[nt]);
      }
    }
    // GELU + pack to bf16 pairs: u[nt][0]=(r0,r1), u[nt][1]=(r2,r3)
    unsigned u[12][2];
    #pragma unroll
    for (int nt = 0; nt < 12; ++nt) {
      u[nt][0] = pack2(gelu_f(acc[nt][0]), gelu_f(acc[nt][1]));
      u[nt][1] = pack2(gelu_f(acc[nt][2]), gelu_f(acc[nt][3]));
    }
    // fc2: for each K-slab kk (32 hid), build B-frag of H^T via shfl:
    // elem j lane l = H[tok=lr][hid = kk*32 + lq*8 + j]
    #pragma unroll
    for (int kk = 0; kk < 6; ++kk) {
      int A0 = __shfl((int)u[2 * kk][0], srcA);
      int B0 = __shfl((int)u[2 * kk + 1][0], srcA);
      int A1 = __shfl((int)u[2 * kk][1], srcA);
      int B1 = __shfl((int)u[2 * kk + 1][1], srcA);
      int A2 = __shfl((int)u[2 * kk][0], srcA + 16);
      int B2 = __shfl((int)u[2 * kk + 1][0], srcA + 16);
      int A3 = __shfl((int)u[2 * kk][1], srcA + 16);
      int B3 = __shfl((int)u[2 * kk + 1][1], srcA + 16);
      i32x4 wv;
      wv[0] = hiSel ? B0 : A0;
      wv[1] = hiSel ? B1 : A1;
      wv[2] = hiSel ? B2 : A2;
      wv[3] = hiSel ? B3 : A3;
      bf16x8 pa = __builtin_bit_cast(bf16x8, wv);
      int kkg = h * 6 + kk;
      #pragma unroll
      for (int ct = 0; ct < 6; ++ct) {
        bf16x8 wf = *(const bf16x8*)&w2b[(size_t)(ct * 16 + lr) * HID + kkg * 32 + lq * 8];
        acc2[ct] = MFMA(wf, pa, acc2[ct]);
      }
    }
  }
  // epilogue: token = wid*16 + lr, f32x4 residual RMW
  {
    float* orow = io + base + (size_t)(wid * 16 + lr) * CCH;
    #pragma unroll
    for (int ct = 0; ct < 6; ++ct) {
      int ch0 = ct * 16 + lq * 4;
      f32x4 cur = *(const f32x4*)(orow + ch0);
      *(f32x4*)(orow + ch0) = cur + acc2[ct];
    }
  }
}

extern "C" void kernel_launch(void* const* d_in, const int* in_sizes, int n_in,
                              void* d_out, int out_size, void* d_ws, size_t ws_size,
                              hipStream_t stream) {
  const float* x    = (const float*)d_in[0];
  const float* n1g  = (const float*)d_in[2];
  const float* n1b  = (const float*)d_in[3];
  const float* qkvw = (const float*)d_in[4];
  const float* qkvb = (const float*)d_in[5];
  const float* pw   = (const float*)d_in[6];
  const float* pb   = (const float*)d_in[7];
  const float* n2g  = (const float*)d_in[8];
  const float* n2b  = (const float*)d_in[9];
  const float* w1   = (const float*)d_in[10];
  const float* b1   = (const float*)d_in[11];
  const float* w2   = (const float*)d_in[12];
  const float* b2   = (const float*)d_in[13];
  float* out = (float*)d_out;

  __hip_bfloat16* xw    = (__hip_bfloat16*)d_ws;
  __hip_bfloat16* obuf  = xw + (size_t)NTOK * CCH;
  __hip_bfloat16* w1b   = obuf + (size_t)NTOK * CCH;
  __hip_bfloat16* w2b   = w1b + HID * CCH;
  __hip_bfloat16* qkvwb = w2b + HID * CCH;
  __hip_bfloat16* pwb   = qkvwb + 3 * CCH * CCH;

  k0_cvt<<<(HID * CCH + 255) / 256, 256, 0, stream>>>(w1, w2, qkvw, pw, w1b, w2b, qkvwb, pwb);
  k1_ln_window<<<NTOK / 8, 256, 0, stream>>>(x, n1g, n1b, xw);
  k2_attn<<<NWIN * 3, 256, 0, stream>>>(xw, qkvwb, qkvb, obuf);
  k3_proj<<<NWIN, 256, 0, stream>>>(obuf, x, pwb, pb, out);
  k4_mlp<<<NTOK / 64, 256, 0, stream>>>(out, n2g, n2b, w1b, b1, w2b, b2);
}

// Round 8
// 475.070 us; speedup vs baseline: 1.0715x; 1.0715x over previous
//
#include <hip/hip_runtime.h>
#include <hip/hip_bf16.h>

// Problem constants (B,D,H,W,C) = (2,32,56,56,96); WS=(2,7,7), SS=(1,3,3)
#define NTOK   200704      // B*D*H*W
#define NWIN   2048        // B * 1024 windows
#define NT     98          // tokens per window (2*7*7)
#define CCH    96
#define HID    384

typedef __attribute__((ext_vector_type(8))) short bf16x8;   // 8 bf16, 4 VGPRs
typedef __attribute__((ext_vector_type(4))) short s16x4;    // 4 bf16, 8 bytes
typedef __attribute__((ext_vector_type(4))) float f32x4;
typedef __attribute__((ext_vector_type(4))) int   i32x4;

#define MFMA(a, b, c) __builtin_amdgcn_mfma_f32_16x16x32_bf16((a), (b), (c), 0, 0, 0)

__device__ __forceinline__ float bf2f(__hip_bfloat16 v) { return __bfloat162float(v); }

__device__ __forceinline__ short f2bf_s(float v) {
  __hip_bfloat16 h = __float2bfloat16(v);
  return *reinterpret_cast<short*>(&h);
}

__device__ __forceinline__ unsigned pack2(float a, float b) {
  unsigned ua = (unsigned short)f2bf_s(a);
  unsigned ub = (unsigned short)f2bf_s(b);
  return ua | (ub << 16);
}

// gelu(x) ~= x * sigmoid(1.5957691x + 0.0713548x^3)  (tanh-form GELU)
__device__ __forceinline__ float gelu_f(float v) {
  float u = v * (1.5957691216057308f + 0.0713548162726f * v * v);
  return __fdividef(v, 1.f + __expf(-u));
}

// ---------------- Kernel 0: convert weights to bf16 -----------------------
__global__ __launch_bounds__(256) void k0_cvt(
    const float* __restrict__ w1, const float* __restrict__ w2,
    const float* __restrict__ qkvw, const float* __restrict__ pw,
    __hip_bfloat16* __restrict__ w1b, __hip_bfloat16* __restrict__ w2b,
    __hip_bfloat16* __restrict__ qkvwb, __hip_bfloat16* __restrict__ pwb) {
  int i = blockIdx.x * 256 + threadIdx.x;
  if (i < HID * CCH) {
    w1b[i] = __float2bfloat16(w1[i]);
    w2b[i] = __float2bfloat16(w2[i]);
  }
  if (i < 3 * CCH * CCH) qkvwb[i] = __float2bfloat16(qkvw[i]);
  if (i < CCH * CCH)     pwb[i]   = __float2bfloat16(pw[i]);
}

// ---------------- Kernel 1: LN1 + shift + window partition -> xw (bf16) ----
__global__ __launch_bounds__(256) void k1_ln_window(
    const float* __restrict__ x, const float* __restrict__ g,
    const float* __restrict__ bt, __hip_bfloat16* __restrict__ xw) {
  int token = blockIdx.x * 8 + (threadIdx.x >> 5);
  int lane = threadIdx.x & 31;
  if (token >= NTOK) return;
  int wb = token / NT;
  int n  = token - wb * NT;
  int b = wb >> 10;
  int rem = wb & 1023;
  int wd = rem >> 6, wh = (rem >> 3) & 7, ww = rem & 7;
  int id = n / 49, ih = (n / 7) % 7, iw = n % 7;
  int dd = wd * 2 + id + 1; if (dd >= 32) dd -= 32;
  int hh = wh * 7 + ih + 3; if (hh >= 56) hh -= 56;
  int w2 = ww * 7 + iw + 3; if (w2 >= 56) w2 -= 56;
  const float* src = x + ((((size_t)b * 32 + dd) * 56 + hh) * 56 + w2) * CCH;
  float v0 = src[lane], v1 = src[lane + 32], v2 = src[lane + 64];
  float s = v0 + v1 + v2, ss = v0 * v0 + v1 * v1 + v2 * v2;
  #pragma unroll
  for (int off = 16; off; off >>= 1) {
    s  += __shfl_xor(s,  off, 32);
    ss += __shfl_xor(ss, off, 32);
  }
  float m   = s * (1.f / 96.f);
  float inv = rsqrtf(ss * (1.f / 96.f) - m * m + 1e-5f);
  __hip_bfloat16* dst = xw + (size_t)token * CCH;
  dst[lane]      = __float2bfloat16((v0 - m) * inv * g[lane]      + bt[lane]);
  dst[lane + 32] = __float2bfloat16((v1 - m) * inv * g[lane + 32] + bt[lane + 32]);
  dst[lane + 64] = __float2bfloat16((v2 - m) * inv * g[lane + 64] + bt[lane + 64]);
}

// ---------------- Kernel 2: per-(window,head) MFMA attention --------------
// No Xs staging, operand-swapped QKV/QK^T/PV, register P, arithmetic mask.
// LDS 25.7KB, 1 barrier. (validated Round 5)
#define QK_S 40     // Q/K row stride (elems)
#define VT_S 120    // V^T row stride (elems); cols 0..111 used
__global__ __launch_bounds__(256, 4) void k2_attn(
    const __hip_bfloat16* __restrict__ xw, const __hip_bfloat16* __restrict__ qkvwb,
    const float* __restrict__ qkv_b, __hip_bfloat16* __restrict__ obuf) {
  __shared__ __align__(16) __hip_bfloat16 Qs[112 * QK_S];   // [token][dim]
  __shared__ __align__(16) __hip_bfloat16 Ks[112 * QK_S];   // [token][dim]
  __shared__ __align__(16) __hip_bfloat16 Vts[32 * VT_S];   // [dim][token]
  __shared__ unsigned char ridL[112];
  int bid = blockIdx.x, tid = threadIdx.x;
  int wb = bid / 3, h = bid - wb * 3;
  int wid = tid >> 6, lane = tid & 63, lr = lane & 15, lq = lane >> 4;
  int mw = wb & 1023;
  int wd = mw >> 6, wh = (mw >> 3) & 7, ww = mw & 7;
  bool hasmask = (wd == 15) || (wh == 7) || (ww == 7);
  const __hip_bfloat16* xp = xw + (size_t)wb * (NT * CCH);
  int h32 = h * 32;

  if (tid < 112) {
    int n = tid < NT ? tid : NT - 1;
    int id = n / 49, r2 = n - id * 49, ih = r2 / 7, iw = r2 - ih * 7;
    int ud = wd * 2 + id, uh = wh * 7 + ih, uw = ww * 7 + iw;
    int dr = (ud < 30) ? 0 : (ud == 30 ? 1 : 2);
    int hr = (uh < 49) ? 0 : (uh < 53 ? 1 : 2);
    int wr = (uw < 49) ? 0 : (uw < 53 ? 1 : 2);
    ridL[tid] = (unsigned char)(dr * 9 + hr * 3 + wr);
  }

  // ---- QKV: 7 token-tiles x 6 out-tiles (Q0,Q1,K0,K1,V0,V1), K=96 ----
  for (int job = wid; job < 42; job += 4) {
    int mt = job / 6, ct = job - (job / 6) * 6;
    int tok = mt * 16 + lr;
    int tokc = tok < NT ? tok : NT - 1;       // clamp: rows >=98 duplicate 97
    const __hip_bfloat16* xrow = xp + (size_t)tokc * CCH;
    bf16x8 xf0 = *(const bf16x8*)(xrow + lq * 8);
    bf16x8 xf1 = *(const bf16x8*)(xrow + 32 + lq * 8);
    bf16x8 xf2 = *(const bf16x8*)(xrow + 64 + lq * 8);
    if (ct < 4) {
      int which = ct >> 1;                    // 0=Q, 1=K
      int grow0 = which * CCH + h32 + (ct & 1) * 16;
      const __hip_bfloat16* wr0 = qkvwb + (size_t)(grow0 + lr) * CCH;
      f32x4 acc = *(const f32x4*)&qkv_b[grow0 + lq * 4];
      acc = MFMA(*(const bf16x8*)(wr0 + lq * 8),      xf0, acc);
      acc = MFMA(*(const bf16x8*)(wr0 + 32 + lq * 8), xf1, acc);
      acc = MFMA(*(const bf16x8*)(wr0 + 64 + lq * 8), xf2, acc);
      if (which == 0) {
        #pragma unroll
        for (int r = 0; r < 4; ++r) acc[r] *= 0.17677669529663689f;
      }
      s16x4 pk4;
      #pragma unroll
      for (int r = 0; r < 4; ++r) pk4[r] = f2bf_s(acc[r]);
      __hip_bfloat16* dst = (which == 0) ? Qs : Ks;
      *(s16x4*)&dst[tok * QK_S + (ct & 1) * 16 + lq * 4] = pk4;
    } else {
      int dt = ct & 1;
      int vrow = 2 * CCH + h32 + dt * 16 + lr;
      const __hip_bfloat16* wv = qkvwb + (size_t)vrow * CCH;
      float bv = qkv_b[vrow];
      f32x4 acc = {bv, bv, bv, bv};
      acc = MFMA(xf0, *(const bf16x8*)(wv + lq * 8),      acc);
      acc = MFMA(xf1, *(const bf16x8*)(wv + 32 + lq * 8), acc);
      acc = MFMA(xf2, *(const bf16x8*)(wv + 64 + lq * 8), acc);
      s16x4 pk4;
      #pragma unroll
      for (int r = 0; r < 4; ++r) pk4[r] = f2bf_s(acc[r]);
      *(s16x4*)&Vts[(dt * 16 + lr) * VT_S + mt * 16 + lq * 4] = pk4;
    }
  }
  __syncthreads();

  // ---- attention: S^T = K*Q^T; softmax per lane (query=lr); O^T = V^T*P^T
  for (int mt = wid; mt < 7; mt += 4) {
    bf16x8 qf = *(const bf16x8*)&Qs[(mt * 16 + lr) * QK_S + lq * 8];
    f32x4 s[7];
    #pragma unroll
    for (int nt = 0; nt < 7; ++nt) s[nt] = {0.f, 0.f, 0.f, 0.f};
    #pragma unroll
    for (int nt = 0; nt < 7; ++nt) {
      bf16x8 kf = *(const bf16x8*)&Ks[(nt * 16 + lr) * QK_S + lq * 8];
      s[nt] = MFMA(kf, qf, s[nt]);   // lane: key = nt*16+lq*4+r, query = mt*16+lr
    }
    if (hasmask) {
      int rq = ridL[mt * 16 + lr];
      #pragma unroll
      for (int nt = 0; nt < 7; ++nt)
        #pragma unroll
        for (int r = 0; r < 4; ++r)
          s[nt][r] += (ridL[nt * 16 + lq * 4 + r] != rq) ? -100.f : 0.f;
    }
    #pragma unroll
    for (int r = 0; r < 4; ++r)   // kill keys 98..111
      s[6][r] = (lq * 4 + r >= 2) ? -1e30f : s[6][r];
    float m = s[0][0];
    #pragma unroll
    for (int nt = 0; nt < 7; ++nt)
      #pragma unroll
      for (int r = 0; r < 4; ++r) m = fmaxf(m, s[nt][r]);
    m = fmaxf(m, __shfl_xor(m, 16));
    m = fmaxf(m, __shfl_xor(m, 32));
    float sum = 0.f;
    #pragma unroll
    for (int nt = 0; nt < 7; ++nt)
      #pragma unroll
      for (int r = 0; r < 4; ++r) {
        float e = __expf(s[nt][r] - m);
        s[nt][r] = e;
        sum += e;
      }
    sum += __shfl_xor(sum, 16);
    sum += __shfl_xor(sum, 32);
    float inv = 1.f / sum;
    #pragma unroll
    for (int nt = 0; nt < 7; ++nt)
      #pragma unroll
      for (int r = 0; r < 4; ++r) s[nt][r] *= inv;
    unsigned pk[6][2];
    #pragma unroll
    for (int nt = 0; nt < 6; ++nt) {
      pk[nt][0] = pack2(s[nt][0], s[nt][1]);
      pk[nt][1] = pack2(s[nt][2], s[nt][3]);
    }
    // PV: build P^T b-frags via shfl (elem j lane l = P[q=lr][ks*32+lq*8+j])
    f32x4 o0 = {0.f, 0.f, 0.f, 0.f}, o1 = {0.f, 0.f, 0.f, 0.f};
    int srcA = lr + ((lq & 1) << 5);
    bool hi = (lq & 2) != 0;
    #pragma unroll
    for (int ks = 0; ks < 3; ++ks) {
      int a0 = __shfl((int)pk[2 * ks][0], srcA);
      int b0 = __shfl((int)pk[2 * ks + 1][0], srcA);
      int a1 = __shfl((int)pk[2 * ks][1], srcA);
      int b1 = __shfl((int)pk[2 * ks + 1][1], srcA);
      int a2 = __shfl((int)pk[2 * ks][0], srcA + 16);
      int b2 = __shfl((int)pk[2 * ks + 1][0], srcA + 16);
      int a3 = __shfl((int)pk[2 * ks][1], srcA + 16);
      int b3 = __shfl((int)pk[2 * ks + 1][1], srcA + 16);
      i32x4 wv4;
      wv4[0] = hi ? b0 : a0;
      wv4[1] = hi ? b1 : a1;
      wv4[2] = hi ? b2 : a2;
      wv4[3] = hi ? b3 : a3;
      bf16x8 pf = __builtin_bit_cast(bf16x8, wv4);
      o0 = MFMA(*(const bf16x8*)&Vts[lr * VT_S + ks * 32 + lq * 8], pf, o0);
      o1 = MFMA(*(const bf16x8*)&Vts[(16 + lr) * VT_S + ks * 32 + lq * 8], pf, o1);
    }
    float p96 = __shfl(s[6][0], lr);
    float p97 = __shfl(s[6][1], lr);
    #pragma unroll
    for (int r = 0; r < 4; ++r) {
      int d0 = lq * 4 + r, d1 = 16 + lq * 4 + r;
      o0[r] += p96 * bf2f(Vts[d0 * VT_S + 96]) + p97 * bf2f(Vts[d0 * VT_S + 97]);
      o1[r] += p96 * bf2f(Vts[d1 * VT_S + 96]) + p97 * bf2f(Vts[d1 * VT_S + 97]);
    }
    int q = mt * 16 + lr;
    if (q < NT) {
      __hip_bfloat16* ob = obuf + ((size_t)wb * NT + q) * CCH + h32;
      s16x4 w0, w1;
      #pragma unroll
      for (int r = 0; r < 4; ++r) { w0[r] = f2bf_s(o0[r]); w1[r] = f2bf_s(o1[r]); }
      *(s16x4*)(ob + lq * 4) = w0;
      *(s16x4*)(ob + 16 + lq * 4) = w1;
    }
  }
}

// ---------------- Kernel 3: MFMA proj + window-reverse + residual ---------
// Operand-swapped proj (D = Wp * os^T): lane holds ONE token and 4
// consecutive channels -> one address calc + f32x4 residual RMW. (R6 win)
#define XS_S 104
__global__ __launch_bounds__(256) void k3_proj(
    const __hip_bfloat16* __restrict__ obuf, const float* __restrict__ x,
    const __hip_bfloat16* __restrict__ pwb, const float* __restrict__ pb,
    float* __restrict__ out) {
  __shared__ __align__(16) __hip_bfloat16 os[112 * XS_S];
  int wb = blockIdx.x, tid = threadIdx.x;
  int wid = tid >> 6, lane = tid & 63, lr = lane & 15, lq = lane >> 4;
  const __hip_bfloat16* src = obuf + (size_t)wb * (NT * CCH);
  for (int q = tid; q < 112 * 12; q += 256) {
    int n = q / 12, g = q - n * 12;
    bf16x8 v = {0, 0, 0, 0, 0, 0, 0, 0};
    if (n < NT) v = *(const bf16x8*)(src + n * CCH + g * 8);
    *(bf16x8*)&os[n * XS_S + g * 8] = v;
  }
  __syncthreads();
  int b = wb >> 10, rem = wb & 1023;
  int wd = rem >> 6, wh = (rem >> 3) & 7, ww = rem & 7;
  for (int job = wid; job < 42; job += 4) {
    int mt = job / 6, ct = job - (job / 6) * 6;
    f32x4 acc = *(const f32x4*)&pb[ct * 16 + lq * 4];
    const __hip_bfloat16* wrow = pwb + (size_t)(ct * 16 + lr) * CCH;
    #pragma unroll
    for (int ks = 0; ks < 3; ++ks) {
      bf16x8 osf = *(const bf16x8*)&os[(mt * 16 + lr) * XS_S + ks * 32 + lq * 8];
      bf16x8 wf  = *(const bf16x8*)(wrow + ks * 32 + lq * 8);
      acc = MFMA(wf, osf, acc);   // D: col=token(lr), row=ch(lq*4+r)
    }
    int token = mt * 16 + lr;
    if (token < NT) {
      int id = token / 49, r2 = token - id * 49;
      int ih = r2 / 7, iw = r2 - ih * 7;
      int dd = wd * 2 + id + 1; if (dd >= 32) dd -= 32;
      int hh = wh * 7 + ih + 3; if (hh >= 56) hh -= 56;
      int w2 = ww * 7 + iw + 3; if (w2 >= 56) w2 -= 56;
      size_t gi = ((((size_t)b * 32 + dd) * 56 + hh) * 56 + w2) * CCH + ct * 16 + lq * 4;
      f32x4 xv = *(const f32x4*)&x[gi];
      *(f32x4*)&out[gi] = xv + acc;
    }
  }
}

// ---------------- Kernel 4: MFMA MLP: LN2 + fc1 + GELU + fc2 + residual ---
// R5 structure (best measured: 165us): 32 tokens/block, LN-A (32 lanes/tok),
// fc1' transposed -> packed b64 swizzled Ht stores, 5 blocks/CU.
// SINGLE CHANGE vs R5: fc2 operand-swapped (identical LDS/weight bytes read;
// lane = one token x 4 consecutive chs) -> f32x4 residual RMW epilogue
// (3 vec loads + 3 vec stores instead of 12+12 scalar).
#define XB_S 104
__global__ __launch_bounds__(256, 5) void k4_mlp(
    float* __restrict__ io, const float* __restrict__ g, const float* __restrict__ bt,
    const __hip_bfloat16* __restrict__ w1b, const float* __restrict__ b1,
    const __hip_bfloat16* __restrict__ w2b, const float* __restrict__ b2) {
  __shared__ __align__(16) __hip_bfloat16 Xb[32 * XB_S];   // 6656 B
  __shared__ __align__(16) __hip_bfloat16 Ht[32 * 384];    // 24576 B, swizzled
  int tid = threadIdx.x;
  size_t base = (size_t)blockIdx.x * 32 * CCH;
  {
    int grp = tid >> 5, lane = tid & 31;
    #pragma unroll
    for (int t0 = 0; t0 < 4; ++t0) {
      int t = grp + t0 * 8;
      const float* src = io + base + (size_t)t * CCH;
      float v0 = src[lane], v1 = src[lane + 32], v2 = src[lane + 64];
      float s = v0 + v1 + v2, ss = v0 * v0 + v1 * v1 + v2 * v2;
      #pragma unroll
      for (int off = 16; off; off >>= 1) {
        s  += __shfl_xor(s,  off, 32);
        ss += __shfl_xor(ss, off, 32);
      }
      float m   = s * (1.f / 96.f);
      float inv = rsqrtf(ss * (1.f / 96.f) - m * m + 1e-5f);
      Xb[t * XB_S + lane]      = __float2bfloat16((v0 - m) * inv * g[lane]      + bt[lane]);
      Xb[t * XB_S + lane + 32] = __float2bfloat16((v1 - m) * inv * g[lane + 32] + bt[lane + 32]);
      Xb[t * XB_S + lane + 64] = __float2bfloat16((v2 - m) * inv * g[lane + 64] + bt[lane + 64]);
    }
  }
  __syncthreads();
  int wid = tid >> 6, lane = tid & 63, lr = lane & 15, lq = lane >> 4;
  // ---- fc1' (transposed): lane holds token=lr, hid 96wid+16nt+lq*4+r ----
  {
    bf16x8 xb[2][3];
    #pragma unroll
    for (int tt = 0; tt < 2; ++tt)
      #pragma unroll
      for (int ks = 0; ks < 3; ++ks)
        xb[tt][ks] = *(const bf16x8*)&Xb[(tt * 16 + lr) * XB_S + ks * 32 + lq * 8];
    f32x4 acc[2][6];
    #pragma unroll
    for (int nt = 0; nt < 6; ++nt) {
      f32x4 bv = *(const f32x4*)&b1[96 * wid + 16 * nt + 4 * lq];
      acc[0][nt] = bv;
      acc[1][nt] = bv;
    }
    const __hip_bfloat16* wrow = w1b + (size_t)(96 * wid + lr) * CCH;
    #pragma unroll
    for (int nt = 0; nt < 6; ++nt) {
      #pragma unroll
      for (int ks = 0; ks < 3; ++ks) {
        bf16x8 a = *(const bf16x8*)(wrow + (size_t)(16 * nt) * CCH + ks * 32 + lq * 8);
        acc[0][nt] = MFMA(a, xb[0][ks], acc[0][nt]);
        acc[1][nt] = MFMA(a, xb[1][ks], acc[1][nt]);
      }
    }
    // GELU + pack 4 bf16 -> one 8B swizzled store per tile
    #pragma unroll
    for (int tt = 0; tt < 2; ++tt) {
      int row = tt * 16 + lr;
      char* hb = (char*)Ht + row * 768;
      int sw = (row & 7) << 4;
      #pragma unroll
      for (int nt = 0; nt < 6; ++nt) {
        s16x4 pk;
        #pragma unroll
        for (int r = 0; r < 4; ++r) pk[r] = f2bf_s(gelu_f(acc[tt][nt][r]));
        *(s16x4*)(hb + ((192 * wid + 32 * nt + 8 * lq) ^ sw)) = pk;
      }
    }
  }
  __syncthreads();
  // ---- fc2 SWAPPED: D = W2 * H^T -> lane: token tt*16+lr, chs 16*nt+lq*4..
  {
    int tt = wid >> 1, ntb = (wid & 1) * 3;
    f32x4 acc2[3];
    #pragma unroll
    for (int j = 0; j < 3; ++j)
      acc2[j] = *(const f32x4*)&b2[16 * (ntb + j) + lq * 4];
    const char* hb = (const char*)Ht + (tt * 16 + lr) * 768;
    int sw = (lr & 7) << 4;
    #pragma unroll 4
    for (int kk = 0; kk < 12; ++kk) {
      bf16x8 hfr = *(const bf16x8*)(hb + ((64 * kk + 16 * lq) ^ sw));
      #pragma unroll
      for (int j = 0; j < 3; ++j) {
        bf16x8 wfr = *(const bf16x8*)&w2b[(size_t)(16 * (ntb + j) + lr) * HID + kk * 32 + lq * 8];
        acc2[j] = MFMA(wfr, hfr, acc2[j]);
      }
    }
    int token = tt * 16 + lr;
    float* orow = io + base + (size_t)token * CCH;
    #pragma unroll
    for (int j = 0; j < 3; ++j) {
      int ch0 = 16 * (ntb + j) + lq * 4;
      f32x4 cur = *(const f32x4*)(orow + ch0);
      *(f32x4*)(orow + ch0) = cur + acc2[j];
    }
  }
}

extern "C" void kernel_launch(void* const* d_in, const int* in_sizes, int n_in,
                              void* d_out, int out_size, void* d_ws, size_t ws_size,
                              hipStream_t stream) {
  const float* x    = (const float*)d_in[0];
  const float* n1g  = (const float*)d_in[2];
  const float* n1b  = (const float*)d_in[3];
  const float* qkvw = (const float*)d_in[4];
  const float* qkvb = (const float*)d_in[5];
  const float* pw   = (const float*)d_in[6];
  const float* pb   = (const float*)d_in[7];
  const float* n2g  = (const float*)d_in[8];
  const float* n2b  = (const float*)d_in[9];
  const float* w1   = (const float*)d_in[10];
  const float* b1   = (const float*)d_in[11];
  const float* w2   = (const float*)d_in[12];
  const float* b2   = (const float*)d_in[13];
  float* out = (float*)d_out;

  __hip_bfloat16* xw    = (__hip_bfloat16*)d_ws;
  __hip_bfloat16* obuf  = xw + (size_t)NTOK * CCH;
  __hip_bfloat16* w1b   = obuf + (size_t)NTOK * CCH;
  __hip_bfloat16* w2b   = w1b + HID * CCH;
  __hip_bfloat16* qkvwb = w2b + HID * CCH;
  __hip_bfloat16* pwb   = qkvwb + 3 * CCH * CCH;

  k0_cvt<<<(HID * CCH + 255) / 256, 256, 0, stream>>>(w1, w2, qkvw, pw, w1b, w2b, qkvwb, pwb);
  k1_ln_window<<<NTOK / 8, 256, 0, stream>>>(x, n1g, n1b, xw);
  k2_attn<<<NWIN * 3, 256, 0, stream>>>(xw, qkvwb, qkvb, obuf);
  k3_proj<<<NWIN, 256, 0, stream>>>(obuf, x, pwb, pb, out);
  k4_mlp<<<NTOK / 32, 256, 0, stream>>>(out, n2g, n2b, w1b, b1, w2b, b2);
}

// Round 9
// 446.347 us; speedup vs baseline: 1.1405x; 1.0644x over previous
//
#include <hip/hip_runtime.h>
#include <hip/hip_bf16.h>

// Problem constants (B,D,H,W,C) = (2,32,56,56,96); WS=(2,7,7), SS=(1,3,3)
#define NTOK   200704      // B*D*H*W
#define NWIN   2048        // B * 1024 windows
#define NT     98          // tokens per window (2*7*7)
#define CCH    96
#define HID    384

typedef __attribute__((ext_vector_type(8))) short bf16x8;   // 8 bf16, 4 VGPRs
typedef __attribute__((ext_vector_type(4))) short s16x4;    // 4 bf16, 8 bytes
typedef __attribute__((ext_vector_type(4))) float f32x4;
typedef __attribute__((ext_vector_type(4))) int   i32x4;

#define MFMA(a, b, c) __builtin_amdgcn_mfma_f32_16x16x32_bf16((a), (b), (c), 0, 0, 0)

__device__ __forceinline__ float bf2f(__hip_bfloat16 v) { return __bfloat162float(v); }

__device__ __forceinline__ short f2bf_s(float v) {
  __hip_bfloat16 h = __float2bfloat16(v);
  return *reinterpret_cast<short*>(&h);
}

__device__ __forceinline__ unsigned pack2(float a, float b) {
  unsigned ua = (unsigned short)f2bf_s(a);
  unsigned ub = (unsigned short)f2bf_s(b);
  return ua | (ub << 16);
}

// gelu(x) ~= x * sigmoid(1.5957691x + 0.0713548x^3)  (tanh-form GELU)
__device__ __forceinline__ float gelu_f(float v) {
  float u = v * (1.5957691216057308f + 0.0713548162726f * v * v);
  return __fdividef(v, 1.f + __expf(-u));
}

// ---------------- Kernel 0: convert weights to bf16 -----------------------
__global__ __launch_bounds__(256) void k0_cvt(
    const float* __restrict__ w1, const float* __restrict__ w2,
    const float* __restrict__ qkvw, const float* __restrict__ pw,
    __hip_bfloat16* __restrict__ w1b, __hip_bfloat16* __restrict__ w2b,
    __hip_bfloat16* __restrict__ qkvwb, __hip_bfloat16* __restrict__ pwb) {
  int i = blockIdx.x * 256 + threadIdx.x;
  if (i < HID * CCH) {
    w1b[i] = __float2bfloat16(w1[i]);
    w2b[i] = __float2bfloat16(w2[i]);
  }
  if (i < 3 * CCH * CCH) qkvwb[i] = __float2bfloat16(qkvw[i]);
  if (i < CCH * CCH)     pwb[i]   = __float2bfloat16(pw[i]);
}

// ---------------- Kernel 1: LN1 + shift + window partition -> xw (bf16) ----
__global__ __launch_bounds__(256) void k1_ln_window(
    const float* __restrict__ x, const float* __restrict__ g,
    const float* __restrict__ bt, __hip_bfloat16* __restrict__ xw) {
  int token = blockIdx.x * 8 + (threadIdx.x >> 5);
  int lane = threadIdx.x & 31;
  if (token >= NTOK) return;
  int wb = token / NT;
  int n  = token - wb * NT;
  int b = wb >> 10;
  int rem = wb & 1023;
  int wd = rem >> 6, wh = (rem >> 3) & 7, ww = rem & 7;
  int id = n / 49, ih = (n / 7) % 7, iw = n % 7;
  int dd = wd * 2 + id + 1; if (dd >= 32) dd -= 32;
  int hh = wh * 7 + ih + 3; if (hh >= 56) hh -= 56;
  int w2 = ww * 7 + iw + 3; if (w2 >= 56) w2 -= 56;
  const float* src = x + ((((size_t)b * 32 + dd) * 56 + hh) * 56 + w2) * CCH;
  float v0 = src[lane], v1 = src[lane + 32], v2 = src[lane + 64];
  float s = v0 + v1 + v2, ss = v0 * v0 + v1 * v1 + v2 * v2;
  #pragma unroll
  for (int off = 16; off; off >>= 1) {
    s  += __shfl_xor(s,  off, 32);
    ss += __shfl_xor(ss, off, 32);
  }
  float m   = s * (1.f / 96.f);
  float inv = rsqrtf(ss * (1.f / 96.f) - m * m + 1e-5f);
  __hip_bfloat16* dst = xw + (size_t)token * CCH;
  dst[lane]      = __float2bfloat16((v0 - m) * inv * g[lane]      + bt[lane]);
  dst[lane + 32] = __float2bfloat16((v1 - m) * inv * g[lane + 32] + bt[lane + 32]);
  dst[lane + 64] = __float2bfloat16((v2 - m) * inv * g[lane + 64] + bt[lane + 64]);
}

// ---------------- Kernel 2: per-(window,head) MFMA attention --------------
// R5-validated structure; QKV loop regrouped as (mt,half) units so the 3 X
// b128 fragments are loaded ONCE per 3 ct-jobs (was once per job): 3x fewer
// global X loads + address VALU. Same math, same stores.
#define QK_S 40     // Q/K row stride (elems)
#define VT_S 120    // V^T row stride (elems); cols 0..111 used
__global__ __launch_bounds__(256, 4) void k2_attn(
    const __hip_bfloat16* __restrict__ xw, const __hip_bfloat16* __restrict__ qkvwb,
    const float* __restrict__ qkv_b, __hip_bfloat16* __restrict__ obuf) {
  __shared__ __align__(16) __hip_bfloat16 Qs[112 * QK_S];   // [token][dim]
  __shared__ __align__(16) __hip_bfloat16 Ks[112 * QK_S];   // [token][dim]
  __shared__ __align__(16) __hip_bfloat16 Vts[32 * VT_S];   // [dim][token]
  __shared__ unsigned char ridL[112];
  int bid = blockIdx.x, tid = threadIdx.x;
  int wb = bid / 3, h = bid - wb * 3;
  int wid = tid >> 6, lane = tid & 63, lr = lane & 15, lq = lane >> 4;
  int mw = wb & 1023;
  int wd = mw >> 6, wh = (mw >> 3) & 7, ww = mw & 7;
  bool hasmask = (wd == 15) || (wh == 7) || (ww == 7);
  const __hip_bfloat16* xp = xw + (size_t)wb * (NT * CCH);
  int h32 = h * 32;

  if (tid < 112) {
    int n = tid < NT ? tid : NT - 1;
    int id = n / 49, r2 = n - id * 49, ih = r2 / 7, iw = r2 - ih * 7;
    int ud = wd * 2 + id, uh = wh * 7 + ih, uw = ww * 7 + iw;
    int dr = (ud < 30) ? 0 : (ud == 30 ? 1 : 2);
    int hr = (uh < 49) ? 0 : (uh < 53 ? 1 : 2);
    int wr = (uw < 49) ? 0 : (uw < 53 ? 1 : 2);
    ridL[tid] = (unsigned char)(dr * 9 + hr * 3 + wr);
  }

  // ---- QKV: 14 units = (mt 0..6) x (half 0..1); each unit covers 3 cts ----
  for (int u = wid; u < 14; u += 4) {
    int mt = u >> 1, half = u & 1;
    int tok = mt * 16 + lr;
    int tokc = tok < NT ? tok : NT - 1;       // clamp: rows >=98 duplicate 97
    const __hip_bfloat16* xrow = xp + (size_t)tokc * CCH;
    bf16x8 xf0 = *(const bf16x8*)(xrow + lq * 8);
    bf16x8 xf1 = *(const bf16x8*)(xrow + 32 + lq * 8);
    bf16x8 xf2 = *(const bf16x8*)(xrow + 64 + lq * 8);
    #pragma unroll
    for (int c = 0; c < 3; ++c) {
      int ct = half * 3 + c;                  // wave-uniform
      if (ct < 4) {
        // swapped: D = W * X^T -> lane holds token=lr, dims lq*4+r
        int which = ct >> 1;                  // 0=Q, 1=K
        int grow0 = which * CCH + h32 + (ct & 1) * 16;
        const __hip_bfloat16* wr0 = qkvwb + (size_t)(grow0 + lr) * CCH;
        f32x4 acc = *(const f32x4*)&qkv_b[grow0 + lq * 4];
        acc = MFMA(*(const bf16x8*)(wr0 + lq * 8),      xf0, acc);
        acc = MFMA(*(const bf16x8*)(wr0 + 32 + lq * 8), xf1, acc);
        acc = MFMA(*(const bf16x8*)(wr0 + 64 + lq * 8), xf2, acc);
        if (which == 0) {
          #pragma unroll
          for (int r = 0; r < 4; ++r) acc[r] *= 0.17677669529663689f;
        }
        s16x4 pk4;
        #pragma unroll
        for (int r = 0; r < 4; ++r) pk4[r] = f2bf_s(acc[r]);
        __hip_bfloat16* dst = (which == 0) ? Qs : Ks;
        *(s16x4*)&dst[tok * QK_S + (ct & 1) * 16 + lq * 4] = pk4;
      } else {
        // plain: D = X * W^T -> lane holds dim=lr, tokens lq*4+r -> V^T rows
        int dt = ct & 1;
        int vrow = 2 * CCH + h32 + dt * 16 + lr;
        const __hip_bfloat16* wv = qkvwb + (size_t)vrow * CCH;
        float bv = qkv_b[vrow];
        f32x4 acc = {bv, bv, bv, bv};
        acc = MFMA(xf0, *(const bf16x8*)(wv + lq * 8),      acc);
        acc = MFMA(xf1, *(const bf16x8*)(wv + 32 + lq * 8), acc);
        acc = MFMA(xf2, *(const bf16x8*)(wv + 64 + lq * 8), acc);
        s16x4 pk4;
        #pragma unroll
        for (int r = 0; r < 4; ++r) pk4[r] = f2bf_s(acc[r]);
        *(s16x4*)&Vts[(dt * 16 + lr) * VT_S + mt * 16 + lq * 4] = pk4;
      }
    }
  }
  __syncthreads();

  // ---- attention: S^T = K*Q^T; softmax per lane (query=lr); O^T = V^T*P^T
  for (int mt = wid; mt < 7; mt += 4) {
    bf16x8 qf = *(const bf16x8*)&Qs[(mt * 16 + lr) * QK_S + lq * 8];
    f32x4 s[7];
    #pragma unroll
    for (int nt = 0; nt < 7; ++nt) s[nt] = {0.f, 0.f, 0.f, 0.f};
    #pragma unroll
    for (int nt = 0; nt < 7; ++nt) {
      bf16x8 kf = *(const bf16x8*)&Ks[(nt * 16 + lr) * QK_S + lq * 8];
      s[nt] = MFMA(kf, qf, s[nt]);   // lane: key = nt*16+lq*4+r, query = mt*16+lr
    }
    if (hasmask) {
      int rq = ridL[mt * 16 + lr];
      #pragma unroll
      for (int nt = 0; nt < 7; ++nt)
        #pragma unroll
        for (int r = 0; r < 4; ++r)
          s[nt][r] += (ridL[nt * 16 + lq * 4 + r] != rq) ? -100.f : 0.f;
    }
    #pragma unroll
    for (int r = 0; r < 4; ++r)   // kill keys 98..111
      s[6][r] = (lq * 4 + r >= 2) ? -1e30f : s[6][r];
    float m = s[0][0];
    #pragma unroll
    for (int nt = 0; nt < 7; ++nt)
      #pragma unroll
      for (int r = 0; r < 4; ++r) m = fmaxf(m, s[nt][r]);
    m = fmaxf(m, __shfl_xor(m, 16));
    m = fmaxf(m, __shfl_xor(m, 32));
    float sum = 0.f;
    #pragma unroll
    for (int nt = 0; nt < 7; ++nt)
      #pragma unroll
      for (int r = 0; r < 4; ++r) {
        float e = __expf(s[nt][r] - m);
        s[nt][r] = e;
        sum += e;
      }
    sum += __shfl_xor(sum, 16);
    sum += __shfl_xor(sum, 32);
    float inv = 1.f / sum;
    #pragma unroll
    for (int nt = 0; nt < 7; ++nt)
      #pragma unroll
      for (int r = 0; r < 4; ++r) s[nt][r] *= inv;
    unsigned pk[6][2];
    #pragma unroll
    for (int nt = 0; nt < 6; ++nt) {
      pk[nt][0] = pack2(s[nt][0], s[nt][1]);
      pk[nt][1] = pack2(s[nt][2], s[nt][3]);
    }
    // PV: build P^T b-frags via shfl (elem j lane l = P[q=lr][ks*32+lq*8+j])
    f32x4 o0 = {0.f, 0.f, 0.f, 0.f}, o1 = {0.f, 0.f, 0.f, 0.f};
    int srcA = lr + ((lq & 1) << 5);
    bool hi = (lq & 2) != 0;
    #pragma unroll
    for (int ks = 0; ks < 3; ++ks) {
      int a0 = __shfl((int)pk[2 * ks][0], srcA);
      int b0 = __shfl((int)pk[2 * ks + 1][0], srcA);
      int a1 = __shfl((int)pk[2 * ks][1], srcA);
      int b1 = __shfl((int)pk[2 * ks + 1][1], srcA);
      int a2 = __shfl((int)pk[2 * ks][0], srcA + 16);
      int b2 = __shfl((int)pk[2 * ks + 1][0], srcA + 16);
      int a3 = __shfl((int)pk[2 * ks][1], srcA + 16);
      int b3 = __shfl((int)pk[2 * ks + 1][1], srcA + 16);
      i32x4 wv4;
      wv4[0] = hi ? b0 : a0;
      wv4[1] = hi ? b1 : a1;
      wv4[2] = hi ? b2 : a2;
      wv4[3] = hi ? b3 : a3;
      bf16x8 pf = __builtin_bit_cast(bf16x8, wv4);
      o0 = MFMA(*(const bf16x8*)&Vts[lr * VT_S + ks * 32 + lq * 8], pf, o0);
      o1 = MFMA(*(const bf16x8*)&Vts[(16 + lr) * VT_S + ks * 32 + lq * 8], pf, o1);
    }
    float p96 = __shfl(s[6][0], lr);
    float p97 = __shfl(s[6][1], lr);
    #pragma unroll
    for (int r = 0; r < 4; ++r) {
      int d0 = lq * 4 + r, d1 = 16 + lq * 4 + r;
      o0[r] += p96 * bf2f(Vts[d0 * VT_S + 96]) + p97 * bf2f(Vts[d0 * VT_S + 97]);
      o1[r] += p96 * bf2f(Vts[d1 * VT_S + 96]) + p97 * bf2f(Vts[d1 * VT_S + 97]);
    }
    int q = mt * 16 + lr;
    if (q < NT) {
      __hip_bfloat16* ob = obuf + ((size_t)wb * NT + q) * CCH + h32;
      s16x4 w0, w1;
      #pragma unroll
      for (int r = 0; r < 4; ++r) { w0[r] = f2bf_s(o0[r]); w1[r] = f2bf_s(o1[r]); }
      *(s16x4*)(ob + lq * 4) = w0;
      *(s16x4*)(ob + 16 + lq * 4) = w1;
    }
  }
}

// ---------------- Kernel 3: MFMA proj + window-reverse + residual ---------
// Operand-swapped proj (D = Wp * os^T): lane holds ONE token and 4
// consecutive channels -> one address calc + f32x4 residual RMW. (R6 win)
#define XS_S 104
__global__ __launch_bounds__(256) void k3_proj(
    const __hip_bfloat16* __restrict__ obuf, const float* __restrict__ x,
    const __hip_bfloat16* __restrict__ pwb, const float* __restrict__ pb,
    float* __restrict__ out) {
  __shared__ __align__(16) __hip_bfloat16 os[112 * XS_S];
  int wb = blockIdx.x, tid = threadIdx.x;
  int wid = tid >> 6, lane = tid & 63, lr = lane & 15, lq = lane >> 4;
  const __hip_bfloat16* src = obuf + (size_t)wb * (NT * CCH);
  for (int q = tid; q < 112 * 12; q += 256) {
    int n = q / 12, g = q - n * 12;
    bf16x8 v = {0, 0, 0, 0, 0, 0, 0, 0};
    if (n < NT) v = *(const bf16x8*)(src + n * CCH + g * 8);
    *(bf16x8*)&os[n * XS_S + g * 8] = v;
  }
  __syncthreads();
  int b = wb >> 10, rem = wb & 1023;
  int wd = rem >> 6, wh = (rem >> 3) & 7, ww = rem & 7;
  for (int job = wid; job < 42; job += 4) {
    int mt = job / 6, ct = job - (job / 6) * 6;
    f32x4 acc = *(const f32x4*)&pb[ct * 16 + lq * 4];
    const __hip_bfloat16* wrow = pwb + (size_t)(ct * 16 + lr) * CCH;
    #pragma unroll
    for (int ks = 0; ks < 3; ++ks) {
      bf16x8 osf = *(const bf16x8*)&os[(mt * 16 + lr) * XS_S + ks * 32 + lq * 8];
      bf16x8 wf  = *(const bf16x8*)(wrow + ks * 32 + lq * 8);
      acc = MFMA(wf, osf, acc);   // D: col=token(lr), row=ch(lq*4+r)
    }
    int token = mt * 16 + lr;
    if (token < NT) {
      int id = token / 49, r2 = token - id * 49;
      int ih = r2 / 7, iw = r2 - ih * 7;
      int dd = wd * 2 + id + 1; if (dd >= 32) dd -= 32;
      int hh = wh * 7 + ih + 3; if (hh >= 56) hh -= 56;
      int w2 = ww * 7 + iw + 3; if (w2 >= 56) w2 -= 56;
      size_t gi = ((((size_t)b * 32 + dd) * 56 + hh) * 56 + w2) * CCH + ct * 16 + lq * 4;
      f32x4 xv = *(const f32x4*)&x[gi];
      *(f32x4*)&out[gi] = xv + acc;
    }
  }
}

// ---------------- Kernel 4: MFMA MLP: LN2 + fc1 + GELU + fc2 + residual ---
// EXACT R5-measured-best structure (165us): 32 tokens/block, LN-A, fc1'
// transposed -> packed b64 swizzled Ht stores, PLAIN fc2 (channel-contiguous
// scalar epilogue), 5 blocks/CU. fc2-swap variant measured +6us (R8) - reverted.
#define XB_S 104
__global__ __launch_bounds__(256, 5) void k4_mlp(
    float* __restrict__ io, const float* __restrict__ g, const float* __restrict__ bt,
    const __hip_bfloat16* __restrict__ w1b, const float* __restrict__ b1,
    const __hip_bfloat16* __restrict__ w2b, const float* __restrict__ b2) {
  __shared__ __align__(16) __hip_bfloat16 Xb[32 * XB_S];   // 6656 B
  __shared__ __align__(16) __hip_bfloat16 Ht[32 * 384];    // 24576 B, swizzled
  int tid = threadIdx.x;
  size_t base = (size_t)blockIdx.x * 32 * CCH;
  {
    int grp = tid >> 5, lane = tid & 31;
    #pragma unroll
    for (int t0 = 0; t0 < 4; ++t0) {
      int t = grp + t0 * 8;
      const float* src = io + base + (size_t)t * CCH;
      float v0 = src[lane], v1 = src[lane + 32], v2 = src[lane + 64];
      float s = v0 + v1 + v2, ss = v0 * v0 + v1 * v1 + v2 * v2;
      #pragma unroll
      for (int off = 16; off; off >>= 1) {
        s  += __shfl_xor(s,  off, 32);
        ss += __shfl_xor(ss, off, 32);
      }
      float m   = s * (1.f / 96.f);
      float inv = rsqrtf(ss * (1.f / 96.f) - m * m + 1e-5f);
      Xb[t * XB_S + lane]      = __float2bfloat16((v0 - m) * inv * g[lane]      + bt[lane]);
      Xb[t * XB_S + lane + 32] = __float2bfloat16((v1 - m) * inv * g[lane + 32] + bt[lane + 32]);
      Xb[t * XB_S + lane + 64] = __float2bfloat16((v2 - m) * inv * g[lane + 64] + bt[lane + 64]);
    }
  }
  __syncthreads();
  int wid = tid >> 6, lane = tid & 63, lr = lane & 15, lq = lane >> 4;
  {
    bf16x8 xb[2][3];
    #pragma unroll
    for (int tt = 0; tt < 2; ++tt)
      #pragma unroll
      for (int ks = 0; ks < 3; ++ks)
        xb[tt][ks] = *(const bf16x8*)&Xb[(tt * 16 + lr) * XB_S + ks * 32 + lq * 8];
    f32x4 acc[2][6];
    #pragma unroll
    for (int nt = 0; nt < 6; ++nt) {
      f32x4 bv = *(const f32x4*)&b1[96 * wid + 16 * nt + 4 * lq];
      acc[0][nt] = bv;
      acc[1][nt] = bv;
    }
    const __hip_bfloat16* wrow = w1b + (size_t)(96 * wid + lr) * CCH;
    #pragma unroll
    for (int nt = 0; nt < 6; ++nt) {
      #pragma unroll
      for (int ks = 0; ks < 3; ++ks) {
        bf16x8 a = *(const bf16x8*)(wrow + (size_t)(16 * nt) * CCH + ks * 32 + lq * 8);
        acc[0][nt] = MFMA(a, xb[0][ks], acc[0][nt]);
        acc[1][nt] = MFMA(a, xb[1][ks], acc[1][nt]);
      }
    }
    // GELU + pack 4 bf16 -> one 8B swizzled store per tile
    #pragma unroll
    for (int tt = 0; tt < 2; ++tt) {
      int row = tt * 16 + lr;
      char* hb = (char*)Ht + row * 768;
      int sw = (row & 7) << 4;
      #pragma unroll
      for (int nt = 0; nt < 6; ++nt) {
        s16x4 pk;
        #pragma unroll
        for (int r = 0; r < 4; ++r) pk[r] = f2bf_s(gelu_f(acc[tt][nt][r]));
        *(s16x4*)(hb + ((192 * wid + 32 * nt + 8 * lq) ^ sw)) = pk;
      }
    }
  }
  __syncthreads();
  {
    int tt = wid >> 1, ntb = (wid & 1) * 3;
    f32x4 acc2[3];
    #pragma unroll
    for (int j = 0; j < 3; ++j) {
      float bv = b2[16 * (ntb + j) + lr];
      acc2[j] = {bv, bv, bv, bv};
    }
    const char* hb = (const char*)Ht + (tt * 16 + lr) * 768;
    int sw = (lr & 7) << 4;
    #pragma unroll 4
    for (int kk = 0; kk < 12; ++kk) {
      bf16x8 a = *(const bf16x8*)(hb + ((64 * kk + 16 * lq) ^ sw));
      #pragma unroll
      for (int j = 0; j < 3; ++j) {
        bf16x8 b = *(const bf16x8*)&w2b[(size_t)(16 * (ntb + j) + lr) * HID + kk * 32 + lq * 8];
        acc2[j] = MFMA(a, b, acc2[j]);
      }
    }
    #pragma unroll
    for (int j = 0; j < 3; ++j)
      #pragma unroll
      for (int r = 0; r < 4; ++r) {
        size_t gi = base + (size_t)(tt * 16 + lq * 4 + r) * CCH + 16 * (ntb + j) + lr;
        io[gi] = io[gi] + acc2[j][r];
      }
  }
}

extern "C" void kernel_launch(void* const* d_in, const int* in_sizes, int n_in,
                              void* d_out, int out_size, void* d_ws, size_t ws_size,
                              hipStream_t stream) {
  const float* x    = (const float*)d_in[0];
  const float* n1g  = (const float*)d_in[2];
  const float* n1b  = (const float*)d_in[3];
  const float* qkvw = (const float*)d_in[4];
  const float* qkvb = (const float*)d_in[5];
  const float* pw   = (const float*)d_in[6];
  const float* pb   = (const float*)d_in[7];
  const float* n2g  = (const float*)d_in[8];
  const float* n2b  = (const float*)d_in[9];
  const float* w1   = (const float*)d_in[10];
  const float* b1   = (const float*)d_in[11];
  const float* w2   = (const float*)d_in[12];
  const float* b2   = (const float*)d_in[13];
  float* out = (float*)d_out;

  __hip_bfloat16* xw    = (__hip_bfloat16*)d_ws;
  __hip_bfloat16* obuf  = xw + (size_t)NTOK * CCH;
  __hip_bfloat16* w1b   = obuf + (size_t)NTOK * CCH;
  __hip_bfloat16* w2b   = w1b + HID * CCH;
  __hip_bfloat16* qkvwb = w2b + HID * CCH;
  __hip_bfloat16* pwb   = qkvwb + 3 * CCH * CCH;

  k0_cvt<<<(HID * CCH + 255) / 256, 256, 0, stream>>>(w1, w2, qkvw, pw, w1b, w2b, qkvwb, pwb);
  k1_ln_window<<<NTOK / 8, 256, 0, stream>>>(x, n1g, n1b, xw);
  k2_attn<<<NWIN * 3, 256, 0, stream>>>(xw, qkvwb, qkvb, obuf);
  k3_proj<<<NWIN, 256, 0, stream>>>(obuf, x, pwb, pb, out);
  k4_mlp<<<NTOK / 32, 256, 0, stream>>>(out, n2g, n2b, w1b, b1, w2b, b2);
}